// Round 9
// baseline (102.318 us; speedup 1.0000x reference)
//
#include <hip/hip_runtime.h>

#define NB 4
#define NC 32
#define NH 32
#define NW 32
#define KK 288                   // 32*3*3 patch length
#define PLANE (NB*NC*NH*NW)      // 131072 elements per plane
#define CE 4                     // channels per block (eighth split)
#define NP 8                     // number of partials

typedef float v2f __attribute__((ext_vector_type(2)));

__device__ __forceinline__ float s3(float v) { return sqrtf(sqrtf(sqrtf(v))); }
__device__ __forceinline__ v2f pkfma(v2f a, v2f b, v2f c) { return __builtin_elementwise_fma(a, b, c); }
__device__ __forceinline__ v2f pkmax(v2f a, v2f b) { return __builtin_elementwise_max(a, b); }

// Zero-mean weight rows; PAIR-INTERLEAVED packed layout for v_pk_* math:
// pair q covers co0 = (q>>3)*16 + (q&7), co1 = co0+8; slot = A/B.
// Per (q,c,r): 8 floats {A.k0,B.k0, A.k1,B.k1, A.k2,B.k2, pad,pad}.
__global__ __launch_bounds__(256) void prep_weights_k(
        const float* __restrict__ w1, const float* __restrict__ w2,
        float* __restrict__ wf1, float* __restrict__ wf2)
{
    const int row = blockIdx.x;                   // 0..63
    const float* src = (row < NC) ? w1 : w2;
    float* dst = (row < NC) ? wf1 : wf2;
    const int co = row & (NC - 1);
    const int tid = threadIdx.x;
    __shared__ float red[256];
    const float a = src[co*KK + tid];                              // tid < 256 < 288
    const float b = (tid + 256 < KK) ? src[co*KK + tid + 256] : 0.0f;
    red[tid] = a + b;
    __syncthreads();
    for (int s = 128; s > 0; s >>= 1) {
        if (tid < s) red[tid] += red[tid + s];
        __syncthreads();
    }
    const float mean = red[0] * (1.0f / (float)KK);
    const int q    = ((co >> 4) << 3) | (co & 7);
    const int slot = (co >> 3) & 1;
    {
        const int e = tid, c = e / 9, r9 = e - c*9, r = r9 / 3, kw = r9 - r*3;
        dst[((q*NC + c)*3 + r)*8 + kw*2 + slot] = a - mean;
    }
    if (tid + 256 < KK) {
        const int e = tid + 256, c = e / 9, r9 = e - c*9, r = r9 / 3, kw = r9 - r*3;
        dst[((q*NC + c)*3 + r)*8 + kw*2 + slot] = b - mean;
    }
}

// Eighth-channel norm-dist conv, MAX-OCCUPANCY variant: 512 thr/block (8 waves),
// 1 px x 2 co(packed) per thread, CE=4 input channels per block.
// Grid = (h=32, ce=8, b=4) -> 1024 blocks x 512 thr = 4 blk/CU = 32 waves/CU
// = 8 waves/SIMD (HW max). __launch_bounds__(512,8) caps VGPR at 64; inner loop
// restructured per-row (2 weight float4 + 3 patch float4 live) to fit.
// LDS tile: xlu-interleaved float4 [c<4][r<3][col<34] (6528 B; 4 blk/CU = 26 KB).
// STAGE1: stages x/l/u. STAGE2: stages s3(sum of 8 eighth-partials).
// Writes partial (pre-root) sums to [ce*PLANE + o], coalesced (32 lanes = 1 row).
template<bool STAGE2>
__global__ __launch_bounds__(512, 8) void normdist_conv_k(
    const float* __restrict__ sy,     // stage1: x plane | stage2: conv1 Y partials [8][PLANE]
    const float* __restrict__ sl,
    const float* __restrict__ su,
    const float* __restrict__ wf,     // prepped pair-interleaved weights
    float* __restrict__ pY, float* __restrict__ pL, float* __restrict__ pU)
{
    const int h    = blockIdx.x;
    const int ce   = blockIdx.y;           // channel eighth 0..7
    const int cq0  = ce * CE;
    const int b    = blockIdx.z;
    const int tid  = threadIdx.x;
    const int wv   = tid >> 6;             // wave id 0..7
    const int lane = tid & 63;
    const int q    = wv*2 + (lane >> 5);   // co pair id 0..15
    const int px   = lane & 31;            // pixel column

    // Patch halo, xlu-interleaved: [c<4][r<3][col<34] float4 (w unused). 6528 B.
    __shared__ float4 sP[CE*3*34];

    for (int i = tid; i < CE*3*34; i += 512) {
        const int c   = i / 102;
        const int rem = i - c*102;
        const int r   = rem / 34;
        const int col = rem - r*34;
        const int gh  = h + r - 1;
        const int gw  = col - 1;
        float vx = 0.0f, vl = 0.0f, vu = 0.0f;
        if ((unsigned)gh < NH && (unsigned)gw < NW) {
            const int g = ((b*NC + cq0 + c)*NH + gh)*NW + gw;
            if (STAGE2) {   // combine 8 eighth-partials + eighth-root (relu no-op: >=0)
                float ax = 0.0f, al = 0.0f, au = 0.0f;
                #pragma unroll
                for (int p = 0; p < NP; ++p) {
                    ax += sy[p*PLANE + g];
                    al += sl[p*PLANE + g];
                    au += su[p*PLANE + g];
                }
                vx = s3(ax); vl = s3(al); vu = s3(au);
            } else {
                vx = sy[g]; vl = sl[g]; vu = su[g];
            }
        }
        sP[i] = make_float4(vx, vl, vu, 0.0f);
    }
    __syncthreads();

    const float4* wq = (const float4*)wf + (q*NC + cq0)*6; // 6 float4 per channel

    v2f aY = {0,0}, aL = {0,0}, aU = {0,0};

    auto tap2 = [&](v2f w, const float4& p) {
        const v2f P  = {p.x, p.x};
        const v2f Lo = {p.y, p.y};
        const v2f Up = {p.z, p.z};
        const v2f d  = P - w;               // y: |d|^8 = ((d^2)^2)^2
        const v2f d2 = d*d, d4 = d2*d2;
        aY = pkfma(d4, d4, aY);
        const v2f a  = Lo - w;              // dl: max(a, nb, 0)^8
        const v2f nb = w - Up;
        const v2f z  = {0.0f, 0.0f};
        const v2f m  = pkmax(pkmax(a, nb), z);
        const v2f m2 = m*m, m4 = m2*m2;
        aL = pkfma(m4, m4, aL);
        const v2f a2 = a*a, q2 = nb*nb;     // du: max(a^2, nb^2)^4
        const v2f mm2 = pkmax(a2, q2);
        const v2f mm4 = mm2*mm2;
        aU = pkfma(mm4, mm4, aU);
    };

    for (int c = 0; c < CE; ++c) {
        const int pb = c*102 + px;
        const float4* wc = wq + c*6;
        // Per-row processing keeps live set small (2 weight f4 + 3 patch f4).
        {   // row 0
            const float4 wlo = wc[0], whi = wc[1];
            const float4 p0 = sP[pb + 0], p1 = sP[pb + 1], p2 = sP[pb + 2];
            tap2((v2f){wlo.x, wlo.y}, p0); tap2((v2f){wlo.z, wlo.w}, p1); tap2((v2f){whi.x, whi.y}, p2);
        }
        {   // row 1
            const float4 wlo = wc[2], whi = wc[3];
            const float4 p0 = sP[pb + 34], p1 = sP[pb + 35], p2 = sP[pb + 36];
            tap2((v2f){wlo.x, wlo.y}, p0); tap2((v2f){wlo.z, wlo.w}, p1); tap2((v2f){whi.x, whi.y}, p2);
        }
        {   // row 2
            const float4 wlo = wc[4], whi = wc[5];
            const float4 p0 = sP[pb + 68], p1 = sP[pb + 69], p2 = sP[pb + 70];
            tap2((v2f){wlo.x, wlo.y}, p0); tap2((v2f){wlo.z, wlo.w}, p1); tap2((v2f){whi.x, whi.y}, p2);
        }
    }

    const int co0 = ((q >> 3) << 4) | (q & 7);   // pair -> co0; co1 = co0 + 8
    const int o   = ((b*NC + co0)*NH + h)*NW + px;
    const int o1  = o + 8*NH*NW;

    float* dY = pY + ce*PLANE;
    float* dL = pL + ce*PLANE;
    float* dU = pU + ce*PLANE;
    dY[o]  = aY.x;  dY[o1] = aY.y;
    dL[o]  = aL.x;  dL[o1] = aL.y;
    dU[o]  = aU.x;  dU[o1] = aU.y;
}

// Combine conv2 eighth-partials, eighth-root, add residual, relu. float4-vectorized.
__global__ __launch_bounds__(256) void epilogue_k(
    const float* __restrict__ pY, const float* __restrict__ pL, const float* __restrict__ pU,
    const float* __restrict__ x,  const float* __restrict__ l,  const float* __restrict__ u,
    float* __restrict__ out)
{
    const int i = blockIdx.x*256 + threadIdx.x;     // float4 index, PLANE/4 total
    const float4* pY4 = (const float4*)pY;
    const float4* pL4 = (const float4*)pL;
    const float4* pU4 = (const float4*)pU;
    const float4* x4  = (const float4*)x;
    const float4* l4  = (const float4*)l;
    const float4* u4  = (const float4*)u;
    float4* out4 = (float4*)out;
    const int Q = PLANE/4;

    float4 ys = {0,0,0,0}, ls = {0,0,0,0}, us = {0,0,0,0};
    #pragma unroll
    for (int p = 0; p < NP; ++p) {
        const float4 ty = pY4[p*Q + i];
        const float4 tl = pL4[p*Q + i];
        const float4 tu = pU4[p*Q + i];
        ys.x += ty.x; ys.y += ty.y; ys.z += ty.z; ys.w += ty.w;
        ls.x += tl.x; ls.y += tl.y; ls.z += tl.z; ls.w += tl.w;
        us.x += tu.x; us.y += tu.y; us.z += tu.z; us.w += tu.w;
    }
    const float4 xr = x4[i], lr = l4[i], ur = u4[i];

    float4 oy, ol, ou;
    oy.x = fmaxf(s3(ys.x) + xr.x, 0.0f);
    oy.y = fmaxf(s3(ys.y) + xr.y, 0.0f);
    oy.z = fmaxf(s3(ys.z) + xr.z, 0.0f);
    oy.w = fmaxf(s3(ys.w) + xr.w, 0.0f);
    ol.x = fmaxf(s3(ls.x) + lr.x, 0.0f);
    ol.y = fmaxf(s3(ls.y) + lr.y, 0.0f);
    ol.z = fmaxf(s3(ls.z) + lr.z, 0.0f);
    ol.w = fmaxf(s3(ls.w) + lr.w, 0.0f);
    ou.x = fmaxf(s3(us.x) + ur.x, 0.0f);
    ou.y = fmaxf(s3(us.y) + ur.y, 0.0f);
    ou.z = fmaxf(s3(us.z) + ur.z, 0.0f);
    ou.w = fmaxf(s3(us.w) + ur.w, 0.0f);

    out4[i]       = oy;
    out4[Q + i]   = ol;
    out4[2*Q + i] = ou;
}

extern "C" void kernel_launch(void* const* d_in, const int* in_sizes, int n_in,
                              void* d_out, int out_size, void* d_ws, size_t ws_size,
                              hipStream_t stream)
{
    const float* x  = (const float*)d_in[0];
    const float* l  = (const float*)d_in[1];
    const float* u  = (const float*)d_in[2];
    const float* w1 = (const float*)d_in[3];
    const float* w2 = (const float*)d_in[4];
    float* ws  = (float*)d_ws;
    float* wf1 = ws;                        // 12288 floats (pair-interleaved layout)
    float* wf2 = wf1 + 12288;
    float* p1Y = wf2 + 12288;               // conv1 partials: [8][PLANE] each
    float* p1L = p1Y + 8*PLANE;
    float* p1U = p1L + 8*PLANE;
    float* p2Y = p1U + 8*PLANE;             // conv2 partials
    float* p2L = p2Y + 8*PLANE;
    float* p2U = p2L + 8*PLANE;
    float* out = (float*)d_out;

    prep_weights_k<<<64, 256, 0, stream>>>(w1, w2, wf1, wf2);

    dim3 grd(NH, 8, NB);                    // h, ce, b -> 1024 blocks
    normdist_conv_k<false><<<grd, 512, 0, stream>>>(x, l, u, wf1, p1Y, p1L, p1U);
    normdist_conv_k<true ><<<grd, 512, 0, stream>>>(p1Y, p1L, p1U, wf2, p2Y, p2L, p2U);
    epilogue_k<<<PLANE/1024, 256, 0, stream>>>(p2Y, p2L, p2U, x, l, u, out);
}

// Round 10
// 100.083 us; speedup vs baseline: 1.0223x; 1.0223x over previous
//
#include <hip/hip_runtime.h>

#define NB 4
#define NC 32
#define NH 32
#define NW 32
#define KK 288                   // 32*3*3 patch length
#define PLANE (NB*NC*NH*NW)      // 131072 elements per plane
#define CQ 8                     // channels per block (quarter split)

typedef float v2f __attribute__((ext_vector_type(2)));

__device__ __forceinline__ float s3(float v) { return sqrtf(sqrtf(sqrtf(v))); }
__device__ __forceinline__ v2f pkfma(v2f a, v2f b, v2f c) { return __builtin_elementwise_fma(a, b, c); }
__device__ __forceinline__ v2f pkmax(v2f a, v2f b) { return __builtin_elementwise_max(a, b); }

// Zero-mean weight rows; PAIR-INTERLEAVED packed layout for v_pk_* math:
// pair q covers co0 = (q>>3)*16 + (q&7), co1 = co0+8; slot = A/B.
// Per (q,c,r): 8 floats {A.k0,B.k0, A.k1,B.k1, A.k2,B.k2, pad,pad}.
__global__ __launch_bounds__(256) void prep_weights_k(
        const float* __restrict__ w1, const float* __restrict__ w2,
        float* __restrict__ wf1, float* __restrict__ wf2)
{
    const int row = blockIdx.x;                   // 0..63
    const float* src = (row < NC) ? w1 : w2;
    float* dst = (row < NC) ? wf1 : wf2;
    const int co = row & (NC - 1);
    const int tid = threadIdx.x;
    __shared__ float red[256];
    const float a = src[co*KK + tid];                              // tid < 256 < 288
    const float b = (tid + 256 < KK) ? src[co*KK + tid + 256] : 0.0f;
    red[tid] = a + b;
    __syncthreads();
    for (int s = 128; s > 0; s >>= 1) {
        if (tid < s) red[tid] += red[tid + s];
        __syncthreads();
    }
    const float mean = red[0] * (1.0f / (float)KK);
    const int q    = ((co >> 4) << 3) | (co & 7);
    const int slot = (co >> 3) & 1;
    {
        const int e = tid, c = e / 9, r9 = e - c*9, r = r9 / 3, kw = r9 - r*3;
        dst[((q*NC + c)*3 + r)*8 + kw*2 + slot] = a - mean;
    }
    if (tid + 256 < KK) {
        const int e = tid + 256, c = e / 9, r9 = e - c*9, r = r9 / 3, kw = r9 - r*3;
        dst[((q*NC + c)*3 + r)*8 + kw*2 + slot] = b - mean;
    }
}

// Quarter-channel norm-dist conv (R8 optimum): 512 thr/block (8 waves),
// 1 px x 2 co(packed) per thread -> 512 blocks x 512 thr = 2 blk/CU =
// 16 waves/CU = 4 waves/SIMD. Block covers one (b,h) row, ALL 32 co, one
// quarter of input channels. Wave = 2 co-pairs (lane>>5) x 32 px (lane&31).
// LDS tile: xlu-interleaved float4 [c<8][r<3][col<34] (13056 B; 2 blk/CU = 26 KB).
// Grid = (h=32, cq=4, b=4) -> 512 blocks.
// STAGE1: stages x/l/u. STAGE2: stages s3(sum of 4 quarter partials).
// Writes partial (pre-root) sums to [cq*PLANE + o], coalesced (32 lanes = 1 row).
template<bool STAGE2>
__global__ __launch_bounds__(512, 4) void normdist_conv_k(
    const float* __restrict__ sy,     // stage1: x plane | stage2: conv1 Y partials [4][PLANE]
    const float* __restrict__ sl,
    const float* __restrict__ su,
    const float* __restrict__ wf,     // prepped pair-interleaved weights
    float* __restrict__ pY, float* __restrict__ pL, float* __restrict__ pU)
{
    const int h    = blockIdx.x;
    const int cq   = blockIdx.y;           // channel quarter 0..3
    const int cq0  = cq * CQ;
    const int b    = blockIdx.z;
    const int tid  = threadIdx.x;
    const int wv   = tid >> 6;             // wave id 0..7
    const int lane = tid & 63;
    const int q    = wv*2 + (lane >> 5);   // co pair id 0..15
    const int px   = lane & 31;            // pixel column

    // Patch halo, xlu-interleaved: [c<8][r<3][col<34] float4 (w unused). 13056 B.
    __shared__ float4 sP[CQ*3*34];

    for (int i = tid; i < CQ*3*34; i += 512) {
        const int c   = i / 102;
        const int rem = i - c*102;
        const int r   = rem / 34;
        const int col = rem - r*34;
        const int gh  = h + r - 1;
        const int gw  = col - 1;
        float vx = 0.0f, vl = 0.0f, vu = 0.0f;
        if ((unsigned)gh < NH && (unsigned)gw < NW) {
            const int g = ((b*NC + cq0 + c)*NH + gh)*NW + gw;
            if (STAGE2) {   // combine 4 quarter partials + eighth-root (relu no-op: >=0)
                vx = s3(sy[g] + sy[PLANE + g] + sy[2*PLANE + g] + sy[3*PLANE + g]);
                vl = s3(sl[g] + sl[PLANE + g] + sl[2*PLANE + g] + sl[3*PLANE + g]);
                vu = s3(su[g] + su[PLANE + g] + su[2*PLANE + g] + su[3*PLANE + g]);
            } else {
                vx = sy[g]; vl = sl[g]; vu = su[g];
            }
        }
        sP[i] = make_float4(vx, vl, vu, 0.0f);
    }
    __syncthreads();

    const float4* wq = (const float4*)wf + (q*NC + cq0)*6; // 6 float4 per channel

    v2f aY = {0,0}, aL = {0,0}, aU = {0,0};

    auto tap2 = [&](v2f w, const float4& p) {
        const v2f P  = {p.x, p.x};
        const v2f Lo = {p.y, p.y};
        const v2f Up = {p.z, p.z};
        const v2f d  = P - w;               // y: |d|^8 = ((d^2)^2)^2
        const v2f d2 = d*d, d4 = d2*d2;
        aY = pkfma(d4, d4, aY);
        const v2f a  = Lo - w;              // dl: max(a, nb, 0)^8
        const v2f nb = w - Up;
        const v2f z  = {0.0f, 0.0f};
        const v2f m  = pkmax(pkmax(a, nb), z);
        const v2f m2 = m*m, m4 = m2*m2;
        aL = pkfma(m4, m4, aL);
        const v2f a2 = a*a, q2 = nb*nb;     // du: max(a^2, nb^2)^4
        const v2f mm2 = pkmax(a2, q2);
        const v2f mm4 = mm2*mm2;
        aU = pkfma(mm4, mm4, aU);
    };

    for (int c = 0; c < CQ; ++c) {
        const int pb = c*102 + px;
        // 3-wide window x 3 rows: window col px-1..px+1 -> LDS idx px..px+2.
        const float4 p00 = sP[pb +  0], p01 = sP[pb +  1], p02 = sP[pb +  2];
        const float4 p10 = sP[pb + 34], p11 = sP[pb + 35], p12 = sP[pb + 36];
        const float4 p20 = sP[pb + 68], p21 = sP[pb + 69], p22 = sP[pb + 70];

        const float4 w0lo = wq[c*6+0], w0hi = wq[c*6+1];   // row 0: {A0,B0,A1,B1},{A2,B2,-,-}
        const float4 w1lo = wq[c*6+2], w1hi = wq[c*6+3];
        const float4 w2lo = wq[c*6+4], w2hi = wq[c*6+5];

        tap2((v2f){w0lo.x, w0lo.y}, p00); tap2((v2f){w0lo.z, w0lo.w}, p01); tap2((v2f){w0hi.x, w0hi.y}, p02);
        tap2((v2f){w1lo.x, w1lo.y}, p10); tap2((v2f){w1lo.z, w1lo.w}, p11); tap2((v2f){w1hi.x, w1hi.y}, p12);
        tap2((v2f){w2lo.x, w2lo.y}, p20); tap2((v2f){w2lo.z, w2lo.w}, p21); tap2((v2f){w2hi.x, w2hi.y}, p22);
    }

    const int co0 = ((q >> 3) << 4) | (q & 7);   // pair -> co0; co1 = co0 + 8
    const int o   = ((b*NC + co0)*NH + h)*NW + px;
    const int o1  = o + 8*NH*NW;

    float* dY = pY + cq*PLANE;
    float* dL = pL + cq*PLANE;
    float* dU = pU + cq*PLANE;
    dY[o]  = aY.x;  dY[o1] = aY.y;
    dL[o]  = aL.x;  dL[o1] = aL.y;
    dU[o]  = aU.x;  dU[o1] = aU.y;
}

// Combine conv2 quarter partials, eighth-root, add residual, relu. float4-vectorized.
__global__ __launch_bounds__(256) void epilogue_k(
    const float* __restrict__ pY, const float* __restrict__ pL, const float* __restrict__ pU,
    const float* __restrict__ x,  const float* __restrict__ l,  const float* __restrict__ u,
    float* __restrict__ out)
{
    const int i = blockIdx.x*256 + threadIdx.x;     // float4 index, PLANE/4 total
    const float4* pY4 = (const float4*)pY;
    const float4* pL4 = (const float4*)pL;
    const float4* pU4 = (const float4*)pU;
    const float4* x4  = (const float4*)x;
    const float4* l4  = (const float4*)l;
    const float4* u4  = (const float4*)u;
    float4* out4 = (float4*)out;
    const int Q = PLANE/4;

    const float4 ya = pY4[i], yb = pY4[Q+i], yc = pY4[2*Q+i], yd = pY4[3*Q+i];
    const float4 la = pL4[i], lb = pL4[Q+i], lc = pL4[2*Q+i], ld = pL4[3*Q+i];
    const float4 ua = pU4[i], ub = pU4[Q+i], uc = pU4[2*Q+i], ud = pU4[3*Q+i];
    const float4 xr = x4[i], lr = l4[i], ur = u4[i];

    float4 oy, ol, ou;
    oy.x = fmaxf(s3(ya.x+yb.x+yc.x+yd.x) + xr.x, 0.0f);
    oy.y = fmaxf(s3(ya.y+yb.y+yc.y+yd.y) + xr.y, 0.0f);
    oy.z = fmaxf(s3(ya.z+yb.z+yc.z+yd.z) + xr.z, 0.0f);
    oy.w = fmaxf(s3(ya.w+yb.w+yc.w+yd.w) + xr.w, 0.0f);
    ol.x = fmaxf(s3(la.x+lb.x+lc.x+ld.x) + lr.x, 0.0f);
    ol.y = fmaxf(s3(la.y+lb.y+lc.y+ld.y) + lr.y, 0.0f);
    ol.z = fmaxf(s3(la.z+lb.z+lc.z+ld.z) + lr.z, 0.0f);
    ol.w = fmaxf(s3(la.w+lb.w+lc.w+ld.w) + lr.w, 0.0f);
    ou.x = fmaxf(s3(ua.x+ub.x+uc.x+ud.x) + ur.x, 0.0f);
    ou.y = fmaxf(s3(ua.y+ub.y+uc.y+ud.y) + ur.y, 0.0f);
    ou.z = fmaxf(s3(ua.z+ub.z+uc.z+ud.z) + ur.z, 0.0f);
    ou.w = fmaxf(s3(ua.w+ub.w+uc.w+ud.w) + ur.w, 0.0f);

    out4[i]       = oy;
    out4[Q + i]   = ol;
    out4[2*Q + i] = ou;
}

extern "C" void kernel_launch(void* const* d_in, const int* in_sizes, int n_in,
                              void* d_out, int out_size, void* d_ws, size_t ws_size,
                              hipStream_t stream)
{
    const float* x  = (const float*)d_in[0];
    const float* l  = (const float*)d_in[1];
    const float* u  = (const float*)d_in[2];
    const float* w1 = (const float*)d_in[3];
    const float* w2 = (const float*)d_in[4];
    float* ws  = (float*)d_ws;
    float* wf1 = ws;                        // 12288 floats (pair-interleaved layout)
    float* wf2 = wf1 + 12288;
    float* p1Y = wf2 + 12288;               // conv1 partials: [4][PLANE] each
    float* p1L = p1Y + 4*PLANE;
    float* p1U = p1L + 4*PLANE;
    float* p2Y = p1U + 4*PLANE;             // conv2 partials
    float* p2L = p2Y + 4*PLANE;
    float* p2U = p2L + 4*PLANE;
    float* out = (float*)d_out;

    prep_weights_k<<<64, 256, 0, stream>>>(w1, w2, wf1, wf2);

    dim3 grd(NH, 4, NB);                    // h, cq, b -> 512 blocks
    normdist_conv_k<false><<<grd, 512, 0, stream>>>(x, l, u, wf1, p1Y, p1L, p1U);
    normdist_conv_k<true ><<<grd, 512, 0, stream>>>(p1Y, p1L, p1U, wf2, p2Y, p2L, p2U);
    epilogue_k<<<PLANE/1024, 256, 0, stream>>>(p2Y, p2L, p2U, x, l, u, out);
}